// Round 12
// baseline (1400.841 us; speedup 1.0000x reference)
//
#include <hip/hip_runtime.h>
#include <hip/hip_fp16.h>

#define NNODES 50000
#define NEDGES 800000
#define IN_F   256
#define HID_F  128
#define OUT_F  16
#define HOPS   30
#define MPAD   50048   // NNODES rounded up to 64-row GEMM tiles

typedef unsigned int u32;
typedef unsigned long long u64;
typedef _Float16 f16;
typedef f16 f16x8 __attribute__((ext_vector_type(8)));
typedef float f32x4 __attribute__((ext_vector_type(4)));
typedef u32 u32x4 __attribute__((ext_vector_type(4)));

union U32H2 { u32 u; __half2 h; };

__device__ inline float2 upk(u32 v) {
    U32H2 t; t.u = v;
    return __half22float2(t.h);
}
__device__ inline u32 pk2(float a, float b) {
    U32H2 t; t.h = __floats2half2_rn(a, b);
    return t.u;
}

// ---------------- graph setup kernels ----------------

__global__ void k_init_deg(int* __restrict__ deg, int n) {
    int i = blockIdx.x * blockDim.x + threadIdx.x;
    if (i < n) deg[i] = 1;  // self-loop
}

__global__ void k_count(const int* __restrict__ dst, int* __restrict__ deg, int e) {
    int i = blockIdx.x * blockDim.x + threadIdx.x;
    if (i < e) atomicAdd(&deg[dst[i]], 1);
}

__global__ void k_dinv(const int* __restrict__ deg, float* __restrict__ dinv, int n) {
    int i = blockIdx.x * blockDim.x + threadIdx.x;
    if (i < n) dinv[i] = rsqrtf((float)deg[i]);
}

__global__ void k_scan1(const int* __restrict__ deg, int* __restrict__ bsums, int n) {
    __shared__ int sh[256];
    int tid = threadIdx.x;
    int i = blockIdx.x * 256 + tid;
    sh[tid] = (i < n) ? deg[i] : 0;
    __syncthreads();
    for (int ofs = 128; ofs > 0; ofs >>= 1) {
        if (tid < ofs) sh[tid] += sh[tid + ofs];
        __syncthreads();
    }
    if (tid == 0) bsums[blockIdx.x] = sh[0];
}

__global__ void k_scan2(int* __restrict__ bsums, int nb, int* __restrict__ rp, int n) {
    if (threadIdx.x == 0 && blockIdx.x == 0) {
        int run = 0;
        for (int b = 0; b < nb; ++b) { int t = bsums[b]; bsums[b] = run; run += t; }
        rp[n] = run;
    }
}

__global__ void k_scan3(const int* __restrict__ deg, const int* __restrict__ bsums,
                        int* __restrict__ rp, int* __restrict__ cursor, int n) {
    __shared__ int sh[256];
    int tid = threadIdx.x;
    int i = blockIdx.x * 256 + tid;
    int v = (i < n) ? deg[i] : 0;
    sh[tid] = v;
    __syncthreads();
    for (int ofs = 1; ofs < 256; ofs <<= 1) {
        int t = 0;
        if (tid >= ofs) t = sh[tid - ofs];
        __syncthreads();
        sh[tid] += t;
        __syncthreads();
    }
    if (i < n) {
        int excl = sh[tid] - v + bsums[blockIdx.x];
        rp[i] = excl;
        cursor[i] = excl;
    }
}

// packed edge: .x = src node, .y = bits of edge weight
__global__ void k_scatter(const int* __restrict__ src, const int* __restrict__ dst,
                          const float* __restrict__ dinv, int* __restrict__ cursor,
                          int2* __restrict__ ew, int e, int n) {
    int t = blockIdx.x * blockDim.x + threadIdx.x;
    if (t < e) {
        int s = src[t], d = dst[t];
        int pos = atomicAdd(&cursor[d], 1);
        ew[pos] = make_int2(s, __float_as_int(dinv[s] * dinv[d]));
    } else if (t < e + n) {
        int i = t - e;
        int pos = atomicAdd(&cursor[i], 1);
        float di = dinv[i];
        ew[pos] = make_int2(i, __float_as_int(di * di));
    }
}

// wave-parallel in-place segment sort by src (one 64-lane wave per node).
__global__ void k_sortwave(const int* __restrict__ rp, int2* __restrict__ ew, int n) {
    int node = blockIdx.x * 4 + (threadIdx.x >> 6);
    int lane = threadIdx.x & 63;
    if (node >= n) return;
    int beg = rp[node], end = rp[node + 1];
    int deg = end - beg;
    if (deg > 64) return;  // leave unsorted (perf-only transform)
    int2 my = make_int2(0x7fffffff, 0);
    if (lane < deg) my = ew[beg + lane];
    int rank = 0;
    for (int k = 0; k < deg; ++k) {
        int sk = __shfl(my.x, k);
        rank += (sk < my.x) || (sk == my.x && k < lane);
    }
    if (lane < deg) ew[beg + rank] = my;
}

// ---- degree-sorted processing order (perf-only permutation) ----
// Waves process 4 nodes in lockstep; runtime = max(deg of 4). Sorting nodes
// by degree makes wave trip counts uniform (E[max4 Poisson17]~22 -> ~17).

__global__ void k_hist(const int* __restrict__ deg, int* __restrict__ hist, int n) {
    int i = blockIdx.x * blockDim.x + threadIdx.x;
    if (i < n) atomicAdd(&hist[min(deg[i], 64)], 1);
}

__global__ void k_histscan(int* __restrict__ hist, int* __restrict__ bincur) {
    if (threadIdx.x == 0 && blockIdx.x == 0) {
        int run = 0;
        for (int b = 0; b <= 64; ++b) { int t = hist[b]; bincur[b] = run; run += t; }
    }
}

__global__ void k_permscatter(const int* __restrict__ deg, int* __restrict__ bincur,
                              int* __restrict__ perm, int n) {
    int i = blockIdx.x * blockDim.x + threadIdx.x;
    if (i < n) {
        int pos = atomicAdd(&bincur[min(deg[i], 64)], 1);
        perm[pos] = i;
    }
}

// W[K][NC] fp32 -> Wt[NC][K] fp16
template<int K, int NC>
__global__ void k_cast_wt(const float* __restrict__ W, f16* __restrict__ Wt) {
    int i = blockIdx.x * blockDim.x + threadIdx.x;
    if (i < K * NC) {
        int k = i / NC, c = i % NC;
        Wt[(size_t)c * K + k] = (f16)W[i];
    }
}

// ------- MFMA GEMM: C[M,128](fp16) = (relu?)(A[M,K] @ Wt^T + b) -------
// 64-row tile, 4 waves x 16 rows, N_rep=8, K-step 32, K-chunked LDS staging
// of BOTH operands (A 16KB + B 32KB per chunk): B fragments come from
// ds_read_b128 instead of 64 serialized global L2 loads (round-11 chain).

template<int K, bool RELU, typename TA>
__global__ __launch_bounds__(256)
void k_gemm_mfma(const TA* __restrict__ A, const f16* __restrict__ Wt,
                 const float* __restrict__ b, f16* __restrict__ C, int M) {
    constexpr int KC = (K > 128) ? 128 : K;   // K-chunk
    __shared__ f16 sa[64][KC + 8];
    __shared__ f16 sb[128][KC + 8];
    int tid  = threadIdx.x;
    int wid  = tid >> 6;
    int lane = tid & 63;
    int row0 = blockIdx.x * 64;
    int rowW = row0 + wid * 16;
    int rl   = lane & 15;
    int kc   = (lane >> 4) * 8;

    f32x4 acc[8];
#pragma unroll
    for (int n = 0; n < 8; ++n) acc[n] = (f32x4)0.f;

    int lr = wid * 16 + rl;

    for (int c = 0; c < K / KC; ++c) {
        int k0 = c * KC;
        if (c > 0) __syncthreads();
        // stage A chunk (64 x KC), coalesced
        if constexpr (sizeof(TA) == 4) {
            const float4* A4 = reinterpret_cast<const float4*>(A);
            constexpr int C4 = KC / 4;
            for (int idx = tid; idx < 64 * C4; idx += 256) {
                int r  = idx / C4;
                int c4 = idx % C4;
                int gr = row0 + r;
                if (gr >= M) gr = M - 1;
                float4 v = A4[(size_t)gr * (K / 4) + k0 / 4 + c4];
                f16 o[4] = {(f16)v.x, (f16)v.y, (f16)v.z, (f16)v.w};
                *reinterpret_cast<u64*>(&sa[r][c4 * 4]) = *reinterpret_cast<u64*>(o);
            }
        } else {
            const u32x4* A4 = reinterpret_cast<const u32x4*>(A);
            constexpr int C8 = KC / 8;
            for (int idx = tid; idx < 64 * C8; idx += 256) {
                int r  = idx / C8;
                int c8 = idx % C8;
                int gr = row0 + r;
                if (gr >= M) gr = M - 1;
                u32x4 v = A4[(size_t)gr * (K / 8) + k0 / 8 + c8];
                *reinterpret_cast<u32x4*>(&sa[r][c8 * 8]) = v;
            }
        }
        // stage B chunk (128 x KC), coalesced
        {
            const u32x4* B4 = reinterpret_cast<const u32x4*>(Wt);
            constexpr int C8 = KC / 8;
            for (int idx = tid; idx < 128 * C8; idx += 256) {
                int r  = idx / C8;
                int c8 = idx % C8;
                u32x4 v = B4[(size_t)r * (K / 8) + k0 / 8 + c8];
                *reinterpret_cast<u32x4*>(&sb[r][c8 * 8]) = v;
            }
        }
        __syncthreads();

#pragma unroll
        for (int kk = 0; kk < KC; kk += 32) {
            f16x8 aF = *reinterpret_cast<const f16x8*>(&sa[lr][kk + kc]);
#pragma unroll
            for (int n = 0; n < 8; ++n) {
                f16x8 bF = *reinterpret_cast<const f16x8*>(&sb[n * 16 + rl][kk + kc]);
                acc[n] = __builtin_amdgcn_mfma_f32_16x16x32_f16(aF, bF, acc[n], 0, 0, 0);
            }
        }
    }

#pragma unroll
    for (int n = 0; n < 8; ++n) {
        int col = n * 16 + rl;
        float bias = b[col];
#pragma unroll
        for (int j = 0; j < 4; ++j) {
            int row = rowW + 4 * (lane >> 4) + j;
            if (row < M) {
                float s = acc[n][j] + bias;
                if (RELU) s = fmaxf(s, 0.f);
                C[(size_t)row * 128 + col] = (f16)s;
            }
        }
    }
}

// ---- propagation at width 128, H in fp16, accumulate fp32 ----
// 16 lanes per node, one u32x4 (8 halves) per lane. Nodes processed in
// degree-sorted order (perm) for uniform wave trip counts.

template<bool RELU>
__global__ void k_proph(const u32* __restrict__ Hin, u32* __restrict__ Hout,
                        const int* __restrict__ rp, const int2* __restrict__ ew,
                        const int* __restrict__ perm, int n) {
    int grp  = threadIdx.x >> 4;   // 16 nodes per block
    int lane = threadIdx.x & 15;
    int g    = blockIdx.x * 16 + grp;
    if (g >= n) return;
    int node = perm[g];
    int beg = rp[node], end = rp[node + 1];
    const u32x4* H4 = reinterpret_cast<const u32x4*>(Hin);  // row = 16 u32x4

    float acc[8];
#pragma unroll
    for (int i = 0; i < 8; ++i) acc[i] = 0.f;

    auto body = [&](int e) {
        int2 p   = ew[e];
        float ww = __int_as_float(p.y);
        u32x4 v  = H4[(size_t)p.x * 16 + lane];
#pragma unroll
        for (int q = 0; q < 4; ++q) {
            float2 f = upk(v[q]);
            acc[q * 2 + 0] += ww * f.x;
            acc[q * 2 + 1] += ww * f.y;
        }
    };

    int e = beg;
    for (; e + 1 < end; e += 2) { body(e); body(e + 1); }
    if (e < end) body(e);

    if (RELU) {
#pragma unroll
        for (int i = 0; i < 8; ++i) acc[i] = fmaxf(acc[i], 0.f);
    }
    u32x4 o;
#pragma unroll
    for (int q = 0; q < 4; ++q) o[q] = pk2(acc[q * 2], acc[q * 2 + 1]);
    reinterpret_cast<u32x4*>(Hout)[(size_t)node * 16 + lane] = o;
}

// ------------- classifier: G[M,16] = Ah[M,128](fp16) @ Wc + bc -------------

__global__ void k_cls_h(const u32* __restrict__ Ah, const float* __restrict__ Wc,
                        const float* __restrict__ bc, float* __restrict__ G, int M) {
    __shared__ float sa[64][132];
    __shared__ float4 sw4[512];
    int tid  = threadIdx.x;
    int row0 = blockIdx.x * 64;

    for (int idx = tid; idx < 512; idx += 256)
        sw4[idx] = reinterpret_cast<const float4*>(Wc)[idx];

    const uint4* A4 = reinterpret_cast<const uint4*>(Ah);
    for (int idx = tid; idx < 64 * 16; idx += 256) {
        int r = idx >> 4, c = idx & 15;
        int gr = row0 + r;
        uint4 v = (gr < M) ? A4[(size_t)gr * 16 + c]
                           : make_uint4(0u, 0u, 0u, 0u);
        float* dst = &sa[r][c * 8];
        const u32* vv = reinterpret_cast<const u32*>(&v);
#pragma unroll
        for (int q = 0; q < 4; ++q) {
            float2 f = upk(vv[q]);
            dst[q * 2 + 0] = f.x;
            dst[q * 2 + 1] = f.y;
        }
    }
    __syncthreads();

    int tc = tid & 3;
    int tr = tid >> 2;
    float4 acc = make_float4(0.f, 0.f, 0.f, 0.f);
    for (int k4 = 0; k4 < 32; ++k4) {
        float4 a = *reinterpret_cast<const float4*>(&sa[tr][k4 * 4]);
        const float* af = reinterpret_cast<const float*>(&a);
#pragma unroll
        for (int kk = 0; kk < 4; ++kk) {
            float4 wv = sw4[(k4 * 4 + kk) * 4 + tc];
            float av = af[kk];
            acc.x += av * wv.x; acc.y += av * wv.y;
            acc.z += av * wv.z; acc.w += av * wv.w;
        }
    }
    int r = row0 + tr;
    if (r < M) {
        float4 bb = reinterpret_cast<const float4*>(bc)[tc];
        acc.x += bb.x; acc.y += bb.y; acc.z += bb.z; acc.w += bb.w;
        reinterpret_cast<float4*>(G)[(size_t)r * 4 + tc] = acc;
    }
}

// ---- final hop at width 16, fp32 ----

__global__ void k_prop16(const float* __restrict__ Gin, float* __restrict__ Out,
                         const int* __restrict__ rp, const int2* __restrict__ ew,
                         int n) {
    int g    = blockIdx.x * 64 + (threadIdx.x >> 2);
    int lane = threadIdx.x & 3;
    if (g >= n) return;
    int beg = rp[g], end = rp[g + 1];
    const float4* G4 = reinterpret_cast<const float4*>(Gin);
    float ax = 0.f, ay = 0.f, az = 0.f, aw = 0.f;
    for (int e = beg; e < end; ++e) {
        int2 p   = ew[e];
        float ww = __int_as_float(p.y);
        float4 hv = G4[(size_t)p.x * 4 + lane];
        ax += ww * hv.x; ay += ww * hv.y; az += ww * hv.z; aw += ww * hv.w;
    }
    reinterpret_cast<float4*>(Out)[(size_t)g * 4 + lane] = make_float4(ax, ay, az, aw);
}

// ---------------- host launch ----------------

extern "C" void kernel_launch(void* const* d_in, const int* in_sizes, int n_in,
                              void* d_out, int out_size, void* d_ws, size_t ws_size,
                              hipStream_t stream) {
    const float* x  = (const float*)d_in[0];
    const float* W1 = (const float*)d_in[1];
    const float* b1 = (const float*)d_in[2];
    const float* W2 = (const float*)d_in[3];
    const float* b2 = (const float*)d_in[4];
    const float* Wc = (const float*)d_in[5];
    const float* bc = (const float*)d_in[6];
    const int*   ei = (const int*)d_in[7];
    const int* srcp = ei;
    const int* dstp = ei + NEDGES;
    float* out = (float*)d_out;

    char* p = (char*)d_ws;
    auto alloc = [&](size_t bytes) -> char* {
        char* r = p;
        p += (bytes + 255) & ~(size_t)255;
        return r;
    };
    int*   deg    = (int*)  alloc(NNODES * 4);
    float* dinv   = (float*)alloc(NNODES * 4);
    int*   rp     = (int*)  alloc((NNODES + 1) * 4);
    int*   cursor = (int*)  alloc(NNODES * 4);
    int*   bsums  = (int*)  alloc(256 * 4);
    int*   hist   = (int*)  alloc(65 * 4);
    int*   bincur = (int*)  alloc(65 * 4);
    int*   perm   = (int*)  alloc(NNODES * 4);
    int2*  ew     = (int2*) alloc((size_t)(NEDGES + NNODES) * 8);  // {src,w}
    f16*   W1t    = (f16*)  alloc((size_t)HID_F * IN_F * 2);   // W1^T fp16
    f16*   W2t    = (f16*)  alloc((size_t)HID_F * HID_F * 2);  // W2^T fp16
    f16*   H0h    = (f16*)  alloc((size_t)MPAD * HID_F * 2);   // gemm1 out (padded)
    u32*   Hh0    = (u32*)  alloc((size_t)MPAD * HID_F * 2);   // prop buffers
    u32*   Hh1    = (u32*)  alloc((size_t)NNODES * HID_F * 2);
    float* G      = (float*)alloc((size_t)NNODES * OUT_F * 4);

    const int T = 256;
    auto nb = [](int n, int t) { return (n + t - 1) / t; };

    // graph norm + CSR build (+ per-node wave sort + degree-sorted perm)
    k_init_deg<<<nb(NNODES, T), T, 0, stream>>>(deg, NNODES);
    k_count<<<nb(NEDGES, T), T, 0, stream>>>(dstp, deg, NEDGES);
    k_dinv<<<nb(NNODES, T), T, 0, stream>>>(deg, dinv, NNODES);
    int NB = nb(NNODES, 256);
    k_scan1<<<NB, 256, 0, stream>>>(deg, bsums, NNODES);
    k_scan2<<<1, 1, 0, stream>>>(bsums, NB, rp, NNODES);
    k_scan3<<<NB, 256, 0, stream>>>(deg, bsums, rp, cursor, NNODES);
    k_scatter<<<nb(NEDGES + NNODES, T), T, 0, stream>>>(srcp, dstp, dinv, cursor,
                                                        ew, NEDGES, NNODES);
    k_sortwave<<<nb(NNODES, 4), 256, 0, stream>>>(rp, ew, NNODES);
    hipMemsetAsync(hist, 0, 65 * 4, stream);
    k_hist<<<nb(NNODES, T), T, 0, stream>>>(deg, hist, NNODES);
    k_histscan<<<1, 1, 0, stream>>>(hist, bincur);
    k_permscatter<<<nb(NNODES, T), T, 0, stream>>>(deg, bincur, perm, NNODES);

    // weight casts
    k_cast_wt<IN_F,  HID_F><<<nb(IN_F * HID_F, T), T, 0, stream>>>(W1, W1t);
    k_cast_wt<HID_F, HID_F><<<nb(HID_F * HID_F, T), T, 0, stream>>>(W2, W2t);

    // dense part on matrix cores: gemm1 f32-in->f16(relu), gemm2 f16->f16
    int GB = MPAD / 64;
    k_gemm_mfma<IN_F,  true,  float><<<GB, 256, 0, stream>>>(x,   W1t, b1, H0h, NNODES);
    k_gemm_mfma<HID_F, false, f16  ><<<GB, 256, 0, stream>>>(H0h, W2t, b2, (f16*)Hh0, NNODES);

    // 30 hops at width 128 in fp16 (degree-sorted order), relu fused into last
    u32* cur = Hh0;
    u32* nxt = Hh1;
    int PB = nb(NNODES, 16);
    for (int i = 0; i < HOPS; ++i) {
        if (i == HOPS - 1)
            k_proph<true ><<<PB, 256, 0, stream>>>(cur, nxt, rp, ew, perm, NNODES);
        else
            k_proph<false><<<PB, 256, 0, stream>>>(cur, nxt, rp, ew, perm, NNODES);
        u32* t = cur; cur = nxt; nxt = t;
    }

    // classifier + final hop at width 16
    k_cls_h<<<nb(NNODES, 64), 256, 0, stream>>>(cur, Wc, bc, G, NNODES);
    k_prop16<<<nb(NNODES, 64), 256, 0, stream>>>(G, out, rp, ew, NNODES);
}

// Round 13
// 1076.094 us; speedup vs baseline: 1.3018x; 1.3018x over previous
//
#include <hip/hip_runtime.h>
#include <hip/hip_fp16.h>

#define NNODES 50000
#define NEDGES 800000
#define IN_F   256
#define HID_F  128
#define OUT_F  16
#define HOPS   30
#define MPAD   50048   // NNODES rounded up to 64-row GEMM tiles

typedef unsigned int u32;
typedef unsigned long long u64;
typedef _Float16 f16;
typedef f16 f16x8 __attribute__((ext_vector_type(8)));
typedef float f32x4 __attribute__((ext_vector_type(4)));
typedef u32 u32x4 __attribute__((ext_vector_type(4)));

union U32H2 { u32 u; __half2 h; };

__device__ inline float2 upk(u32 v) {
    U32H2 t; t.u = v;
    return __half22float2(t.h);
}
__device__ inline u32 pk2(float a, float b) {
    U32H2 t; t.h = __floats2half2_rn(a, b);
    return t.u;
}

// ---------------- graph setup kernels ----------------

__global__ void k_init_deg(int* __restrict__ deg, int n) {
    int i = blockIdx.x * blockDim.x + threadIdx.x;
    if (i < n) deg[i] = 1;  // self-loop
}

__global__ void k_count(const int* __restrict__ dst, int* __restrict__ deg, int e) {
    int i = blockIdx.x * blockDim.x + threadIdx.x;
    if (i < e) atomicAdd(&deg[dst[i]], 1);
}

__global__ void k_dinv(const int* __restrict__ deg, float* __restrict__ dinv, int n) {
    int i = blockIdx.x * blockDim.x + threadIdx.x;
    if (i < n) dinv[i] = rsqrtf((float)deg[i]);
}

__global__ void k_scan1(const int* __restrict__ deg, int* __restrict__ bsums, int n) {
    __shared__ int sh[256];
    int tid = threadIdx.x;
    int i = blockIdx.x * 256 + tid;
    sh[tid] = (i < n) ? deg[i] : 0;
    __syncthreads();
    for (int ofs = 128; ofs > 0; ofs >>= 1) {
        if (tid < ofs) sh[tid] += sh[tid + ofs];
        __syncthreads();
    }
    if (tid == 0) bsums[blockIdx.x] = sh[0];
}

__global__ void k_scan2(int* __restrict__ bsums, int nb, int* __restrict__ rp, int n) {
    if (threadIdx.x == 0 && blockIdx.x == 0) {
        int run = 0;
        for (int b = 0; b < nb; ++b) { int t = bsums[b]; bsums[b] = run; run += t; }
        rp[n] = run;
    }
}

__global__ void k_scan3(const int* __restrict__ deg, const int* __restrict__ bsums,
                        int* __restrict__ rp, int* __restrict__ cursor, int n) {
    __shared__ int sh[256];
    int tid = threadIdx.x;
    int i = blockIdx.x * 256 + tid;
    int v = (i < n) ? deg[i] : 0;
    sh[tid] = v;
    __syncthreads();
    for (int ofs = 1; ofs < 256; ofs <<= 1) {
        int t = 0;
        if (tid >= ofs) t = sh[tid - ofs];
        __syncthreads();
        sh[tid] += t;
        __syncthreads();
    }
    if (i < n) {
        int excl = sh[tid] - v + bsums[blockIdx.x];
        rp[i] = excl;
        cursor[i] = excl;
    }
}

// packed edge: .x = src node, .y = bits of edge weight
__global__ void k_scatter(const int* __restrict__ src, const int* __restrict__ dst,
                          const float* __restrict__ dinv, int* __restrict__ cursor,
                          int2* __restrict__ ew, int e, int n) {
    int t = blockIdx.x * blockDim.x + threadIdx.x;
    if (t < e) {
        int s = src[t], d = dst[t];
        int pos = atomicAdd(&cursor[d], 1);
        ew[pos] = make_int2(s, __float_as_int(dinv[s] * dinv[d]));
    } else if (t < e + n) {
        int i = t - e;
        int pos = atomicAdd(&cursor[i], 1);
        float di = dinv[i];
        ew[pos] = make_int2(i, __float_as_int(di * di));
    }
}

// wave-parallel in-place segment sort by src (one 64-lane wave per node).
__global__ void k_sortwave(const int* __restrict__ rp, int2* __restrict__ ew, int n) {
    int node = blockIdx.x * 4 + (threadIdx.x >> 6);
    int lane = threadIdx.x & 63;
    if (node >= n) return;
    int beg = rp[node], end = rp[node + 1];
    int deg = end - beg;
    if (deg > 64) return;  // leave unsorted (perf-only transform)
    int2 my = make_int2(0x7fffffff, 0);
    if (lane < deg) my = ew[beg + lane];
    int rank = 0;
    for (int k = 0; k < deg; ++k) {
        int sk = __shfl(my.x, k);
        rank += (sk < my.x) || (sk == my.x && k < lane);
    }
    if (lane < deg) ew[beg + rank] = my;
}

// W[K][NC] fp32 -> Wt[NC][K] fp16
template<int K, int NC>
__global__ void k_cast_wt(const float* __restrict__ W, f16* __restrict__ Wt) {
    int i = blockIdx.x * blockDim.x + threadIdx.x;
    if (i < K * NC) {
        int k = i / NC, c = i % NC;
        Wt[(size_t)c * K + k] = (f16)W[i];
    }
}

// ------- MFMA GEMM: C[M,128](fp16) = (relu?)(A[M,K] @ Wt^T + b) -------
// 64-row tile, 4 waves x 16 rows, N_rep=8, K-step 32, K-chunked LDS staging
// of BOTH operands (A 16KB + B 32KB per chunk): B fragments come from
// ds_read_b128 instead of 64 serialized global L2 loads (round-11 chain).

template<int K, bool RELU, typename TA>
__global__ __launch_bounds__(256)
void k_gemm_mfma(const TA* __restrict__ A, const f16* __restrict__ Wt,
                 const float* __restrict__ b, f16* __restrict__ C, int M) {
    constexpr int KC = (K > 128) ? 128 : K;   // K-chunk
    __shared__ f16 sa[64][KC + 8];
    __shared__ f16 sb[128][KC + 8];
    int tid  = threadIdx.x;
    int wid  = tid >> 6;
    int lane = tid & 63;
    int row0 = blockIdx.x * 64;
    int rowW = row0 + wid * 16;
    int rl   = lane & 15;
    int kc   = (lane >> 4) * 8;

    f32x4 acc[8];
#pragma unroll
    for (int n = 0; n < 8; ++n) acc[n] = (f32x4)0.f;

    int lr = wid * 16 + rl;

    for (int c = 0; c < K / KC; ++c) {
        int k0 = c * KC;
        if (c > 0) __syncthreads();
        // stage A chunk (64 x KC), coalesced
        if constexpr (sizeof(TA) == 4) {
            const float4* A4 = reinterpret_cast<const float4*>(A);
            constexpr int C4 = KC / 4;
            for (int idx = tid; idx < 64 * C4; idx += 256) {
                int r  = idx / C4;
                int c4 = idx % C4;
                int gr = row0 + r;
                if (gr >= M) gr = M - 1;
                float4 v = A4[(size_t)gr * (K / 4) + k0 / 4 + c4];
                f16 o[4] = {(f16)v.x, (f16)v.y, (f16)v.z, (f16)v.w};
                *reinterpret_cast<u64*>(&sa[r][c4 * 4]) = *reinterpret_cast<u64*>(o);
            }
        } else {
            const u32x4* A4 = reinterpret_cast<const u32x4*>(A);
            constexpr int C8 = KC / 8;
            for (int idx = tid; idx < 64 * C8; idx += 256) {
                int r  = idx / C8;
                int c8 = idx % C8;
                int gr = row0 + r;
                if (gr >= M) gr = M - 1;
                u32x4 v = A4[(size_t)gr * (K / 8) + k0 / 8 + c8];
                *reinterpret_cast<u32x4*>(&sa[r][c8 * 8]) = v;
            }
        }
        // stage B chunk (128 x KC), coalesced
        {
            const u32x4* B4 = reinterpret_cast<const u32x4*>(Wt);
            constexpr int C8 = KC / 8;
            for (int idx = tid; idx < 128 * C8; idx += 256) {
                int r  = idx / C8;
                int c8 = idx % C8;
                u32x4 v = B4[(size_t)r * (K / 8) + k0 / 8 + c8];
                *reinterpret_cast<u32x4*>(&sb[r][c8 * 8]) = v;
            }
        }
        __syncthreads();

#pragma unroll
        for (int kk = 0; kk < KC; kk += 32) {
            f16x8 aF = *reinterpret_cast<const f16x8*>(&sa[lr][kk + kc]);
#pragma unroll
            for (int n = 0; n < 8; ++n) {
                f16x8 bF = *reinterpret_cast<const f16x8*>(&sb[n * 16 + rl][kk + kc]);
                acc[n] = __builtin_amdgcn_mfma_f32_16x16x32_f16(aF, bF, acc[n], 0, 0, 0);
            }
        }
    }

#pragma unroll
    for (int n = 0; n < 8; ++n) {
        int col = n * 16 + rl;
        float bias = b[col];
#pragma unroll
        for (int j = 0; j < 4; ++j) {
            int row = rowW + 4 * (lane >> 4) + j;
            if (row < M) {
                float s = acc[n][j] + bias;
                if (RELU) s = fmaxf(s, 0.f);
                C[(size_t)row * 128 + col] = (f16)s;
            }
        }
    }
}

// ---- propagation at width 128, H in fp16, accumulate fp32 ----
// 16 lanes per node, one u32x4 (8 halves) per lane.

template<bool RELU>
__global__ void k_proph(const u32* __restrict__ Hin, u32* __restrict__ Hout,
                        const int* __restrict__ rp, const int2* __restrict__ ew,
                        int n) {
    int grp  = threadIdx.x >> 4;   // 16 nodes per block
    int lane = threadIdx.x & 15;
    int node = blockIdx.x * 16 + grp;
    if (node >= n) return;
    int beg = rp[node], end = rp[node + 1];
    const u32x4* H4 = reinterpret_cast<const u32x4*>(Hin);  // row = 16 u32x4

    float acc[8];
#pragma unroll
    for (int i = 0; i < 8; ++i) acc[i] = 0.f;

    auto body = [&](int e) {
        int2 p   = ew[e];
        float ww = __int_as_float(p.y);
        u32x4 v  = H4[(size_t)p.x * 16 + lane];
#pragma unroll
        for (int q = 0; q < 4; ++q) {
            float2 f = upk(v[q]);
            acc[q * 2 + 0] += ww * f.x;
            acc[q * 2 + 1] += ww * f.y;
        }
    };

    int e = beg;
    for (; e + 1 < end; e += 2) { body(e); body(e + 1); }
    if (e < end) body(e);

    if (RELU) {
#pragma unroll
        for (int i = 0; i < 8; ++i) acc[i] = fmaxf(acc[i], 0.f);
    }
    u32x4 o;
#pragma unroll
    for (int q = 0; q < 4; ++q) o[q] = pk2(acc[q * 2], acc[q * 2 + 1]);
    reinterpret_cast<u32x4*>(Hout)[(size_t)node * 16 + lane] = o;
}

// ------------- classifier: G[M,16] = Ah[M,128](fp16) @ Wc + bc -------------

__global__ void k_cls_h(const u32* __restrict__ Ah, const float* __restrict__ Wc,
                        const float* __restrict__ bc, float* __restrict__ G, int M) {
    __shared__ float sa[64][132];
    __shared__ float4 sw4[512];
    int tid  = threadIdx.x;
    int row0 = blockIdx.x * 64;

    for (int idx = tid; idx < 512; idx += 256)
        sw4[idx] = reinterpret_cast<const float4*>(Wc)[idx];

    const uint4* A4 = reinterpret_cast<const uint4*>(Ah);
    for (int idx = tid; idx < 64 * 16; idx += 256) {
        int r = idx >> 4, c = idx & 15;
        int gr = row0 + r;
        uint4 v = (gr < M) ? A4[(size_t)gr * 16 + c]
                           : make_uint4(0u, 0u, 0u, 0u);
        float* dst = &sa[r][c * 8];
        const u32* vv = reinterpret_cast<const u32*>(&v);
#pragma unroll
        for (int q = 0; q < 4; ++q) {
            float2 f = upk(vv[q]);
            dst[q * 2 + 0] = f.x;
            dst[q * 2 + 1] = f.y;
        }
    }
    __syncthreads();

    int tc = tid & 3;
    int tr = tid >> 2;
    float4 acc = make_float4(0.f, 0.f, 0.f, 0.f);
    for (int k4 = 0; k4 < 32; ++k4) {
        float4 a = *reinterpret_cast<const float4*>(&sa[tr][k4 * 4]);
        const float* af = reinterpret_cast<const float*>(&a);
#pragma unroll
        for (int kk = 0; kk < 4; ++kk) {
            float4 wv = sw4[(k4 * 4 + kk) * 4 + tc];
            float av = af[kk];
            acc.x += av * wv.x; acc.y += av * wv.y;
            acc.z += av * wv.z; acc.w += av * wv.w;
        }
    }
    int r = row0 + tr;
    if (r < M) {
        float4 bb = reinterpret_cast<const float4*>(bc)[tc];
        acc.x += bb.x; acc.y += bb.y; acc.z += bb.z; acc.w += bb.w;
        reinterpret_cast<float4*>(G)[(size_t)r * 4 + tc] = acc;
    }
}

// ---- final hop at width 16, fp32 ----

__global__ void k_prop16(const float* __restrict__ Gin, float* __restrict__ Out,
                         const int* __restrict__ rp, const int2* __restrict__ ew,
                         int n) {
    int g    = blockIdx.x * 64 + (threadIdx.x >> 2);
    int lane = threadIdx.x & 3;
    if (g >= n) return;
    int beg = rp[g], end = rp[g + 1];
    const float4* G4 = reinterpret_cast<const float4*>(Gin);
    float ax = 0.f, ay = 0.f, az = 0.f, aw = 0.f;
    for (int e = beg; e < end; ++e) {
        int2 p   = ew[e];
        float ww = __int_as_float(p.y);
        float4 hv = G4[(size_t)p.x * 4 + lane];
        ax += ww * hv.x; ay += ww * hv.y; az += ww * hv.z; aw += ww * hv.w;
    }
    reinterpret_cast<float4*>(Out)[(size_t)g * 4 + lane] = make_float4(ax, ay, az, aw);
}

// ---------------- host launch ----------------

extern "C" void kernel_launch(void* const* d_in, const int* in_sizes, int n_in,
                              void* d_out, int out_size, void* d_ws, size_t ws_size,
                              hipStream_t stream) {
    const float* x  = (const float*)d_in[0];
    const float* W1 = (const float*)d_in[1];
    const float* b1 = (const float*)d_in[2];
    const float* W2 = (const float*)d_in[3];
    const float* b2 = (const float*)d_in[4];
    const float* Wc = (const float*)d_in[5];
    const float* bc = (const float*)d_in[6];
    const int*   ei = (const int*)d_in[7];
    const int* srcp = ei;
    const int* dstp = ei + NEDGES;
    float* out = (float*)d_out;

    char* p = (char*)d_ws;
    auto alloc = [&](size_t bytes) -> char* {
        char* r = p;
        p += (bytes + 255) & ~(size_t)255;
        return r;
    };
    int*   deg    = (int*)  alloc(NNODES * 4);
    float* dinv   = (float*)alloc(NNODES * 4);
    int*   rp     = (int*)  alloc((NNODES + 1) * 4);
    int*   cursor = (int*)  alloc(NNODES * 4);
    int*   bsums  = (int*)  alloc(256 * 4);
    int2*  ew     = (int2*) alloc((size_t)(NEDGES + NNODES) * 8);  // {src,w}
    f16*   W1t    = (f16*)  alloc((size_t)HID_F * IN_F * 2);   // W1^T fp16
    f16*   W2t    = (f16*)  alloc((size_t)HID_F * HID_F * 2);  // W2^T fp16
    f16*   H0h    = (f16*)  alloc((size_t)MPAD * HID_F * 2);   // gemm1 out (padded)
    u32*   Hh0    = (u32*)  alloc((size_t)MPAD * HID_F * 2);   // prop buffers
    u32*   Hh1    = (u32*)  alloc((size_t)NNODES * HID_F * 2);
    float* G      = (float*)alloc((size_t)NNODES * OUT_F * 4);

    const int T = 256;
    auto nb = [](int n, int t) { return (n + t - 1) / t; };

    // graph norm + CSR build (+ per-node wave sort)
    k_init_deg<<<nb(NNODES, T), T, 0, stream>>>(deg, NNODES);
    k_count<<<nb(NEDGES, T), T, 0, stream>>>(dstp, deg, NEDGES);
    k_dinv<<<nb(NNODES, T), T, 0, stream>>>(deg, dinv, NNODES);
    int NB = nb(NNODES, 256);
    k_scan1<<<NB, 256, 0, stream>>>(deg, bsums, NNODES);
    k_scan2<<<1, 1, 0, stream>>>(bsums, NB, rp, NNODES);
    k_scan3<<<NB, 256, 0, stream>>>(deg, bsums, rp, cursor, NNODES);
    k_scatter<<<nb(NEDGES + NNODES, T), T, 0, stream>>>(srcp, dstp, dinv, cursor,
                                                        ew, NEDGES, NNODES);
    k_sortwave<<<nb(NNODES, 4), 256, 0, stream>>>(rp, ew, NNODES);

    // weight casts
    k_cast_wt<IN_F,  HID_F><<<nb(IN_F * HID_F, T), T, 0, stream>>>(W1, W1t);
    k_cast_wt<HID_F, HID_F><<<nb(HID_F * HID_F, T), T, 0, stream>>>(W2, W2t);

    // dense part on matrix cores: gemm1 f32-in->f16(relu), gemm2 f16->f16
    int GB = MPAD / 64;
    k_gemm_mfma<IN_F,  true,  float><<<GB, 256, 0, stream>>>(x,   W1t, b1, H0h, NNODES);
    k_gemm_mfma<HID_F, false, f16  ><<<GB, 256, 0, stream>>>(H0h, W2t, b2, (f16*)Hh0, NNODES);

    // 30 hops at width 128 in fp16, relu fused into last hop
    u32* cur = Hh0;
    u32* nxt = Hh1;
    int PB = nb(NNODES, 16);
    for (int i = 0; i < HOPS; ++i) {
        if (i == HOPS - 1)
            k_proph<true ><<<PB, 256, 0, stream>>>(cur, nxt, rp, ew, NNODES);
        else
            k_proph<false><<<PB, 256, 0, stream>>>(cur, nxt, rp, ew, NNODES);
        u32* t = cur; cur = nxt; nxt = t;
    }

    // classifier + final hop at width 16
    k_cls_h<<<nb(NNODES, 64), 256, 0, stream>>>(cur, Wc, bc, G, NNODES);
    k_prop16<<<nb(NNODES, 64), 256, 0, stream>>>(G, out, rp, ew, NNODES);
}

// Round 14
// 1053.481 us; speedup vs baseline: 1.3297x; 1.0215x over previous
//
#include <hip/hip_runtime.h>
#include <hip/hip_fp16.h>

#define NNODES 50000
#define NEDGES 800000
#define IN_F   256
#define HID_F  128
#define OUT_F  16
#define HOPS   30
#define MPAD   50048   // NNODES rounded up to 64-row GEMM tiles
#define GB_GEMM (MPAD / 64)

typedef unsigned int u32;
typedef unsigned long long u64;
typedef _Float16 f16;
typedef f16 f16x8 __attribute__((ext_vector_type(8)));
typedef float f32x4 __attribute__((ext_vector_type(4)));
typedef u32 u32x4 __attribute__((ext_vector_type(4)));

union U32H2 { u32 u; __half2 h; };

__device__ inline float2 upk(u32 v) {
    U32H2 t; t.u = v;
    return __half22float2(t.h);
}
__device__ inline u32 pk2(float a, float b) {
    U32H2 t; t.h = __floats2half2_rn(a, b);
    return t.u;
}

// ---------------- graph setup kernels ----------------

__global__ void k_init_deg(int* __restrict__ deg, int n) {
    int i = blockIdx.x * blockDim.x + threadIdx.x;
    if (i < n) deg[i] = 1;  // self-loop
}

__global__ void k_count(const int* __restrict__ dst, int* __restrict__ deg, int e) {
    int i = blockIdx.x * blockDim.x + threadIdx.x;
    if (i < e) atomicAdd(&deg[dst[i]], 1);
}

__global__ void k_dinv(const int* __restrict__ deg, float* __restrict__ dinv, int n) {
    int i = blockIdx.x * blockDim.x + threadIdx.x;
    if (i < n) dinv[i] = rsqrtf((float)deg[i]);
}

__global__ void k_scan1(const int* __restrict__ deg, int* __restrict__ bsums, int n) {
    __shared__ int sh[256];
    int tid = threadIdx.x;
    int i = blockIdx.x * 256 + tid;
    sh[tid] = (i < n) ? deg[i] : 0;
    __syncthreads();
    for (int ofs = 128; ofs > 0; ofs >>= 1) {
        if (tid < ofs) sh[tid] += sh[tid + ofs];
        __syncthreads();
    }
    if (tid == 0) bsums[blockIdx.x] = sh[0];
}

__global__ void k_scan2(int* __restrict__ bsums, int nb, int* __restrict__ rp, int n) {
    if (threadIdx.x == 0 && blockIdx.x == 0) {
        int run = 0;
        for (int b = 0; b < nb; ++b) { int t = bsums[b]; bsums[b] = run; run += t; }
        rp[n] = run;
    }
}

__global__ void k_scan3(const int* __restrict__ deg, const int* __restrict__ bsums,
                        int* __restrict__ rp, int* __restrict__ cursor, int n) {
    __shared__ int sh[256];
    int tid = threadIdx.x;
    int i = blockIdx.x * 256 + tid;
    int v = (i < n) ? deg[i] : 0;
    sh[tid] = v;
    __syncthreads();
    for (int ofs = 1; ofs < 256; ofs <<= 1) {
        int t = 0;
        if (tid >= ofs) t = sh[tid - ofs];
        __syncthreads();
        sh[tid] += t;
        __syncthreads();
    }
    if (i < n) {
        int excl = sh[tid] - v + bsums[blockIdx.x];
        rp[i] = excl;
        cursor[i] = excl;
    }
}

// W[K][NC] fp32 -> Wt[NC][K] fp16
template<int K, int NC>
__global__ void k_cast_wt(const float* __restrict__ W, f16* __restrict__ Wt) {
    int i = blockIdx.x * blockDim.x + threadIdx.x;
    if (i < K * NC) {
        int k = i / NC, c = i % NC;
        Wt[(size_t)c * K + k] = (f16)W[i];
    }
}

// ---- GEMM tile device body: C[M,128](fp16) = (relu?)(A[M,K] @ Wt^T + b) ----
// 64-row tile, 4 waves x 16 rows, N_rep=8, KC=64 chunks, both operands
// staged through LDS with register-batched loads (all 8 global loads in
// flight before any LDS write). LDS 27.6KB -> 4-5 blocks/CU.

template<int K, bool RELU, typename TA>
__device__ void gemm_tile(const TA* __restrict__ A, const f16* __restrict__ Wt,
                          const float* __restrict__ b, f16* __restrict__ C,
                          int M, int bid) {
    constexpr int KC = 64;
    __shared__ f16 sa[64][KC + 8];
    __shared__ f16 sb[128][KC + 8];
    int tid  = threadIdx.x;
    int wid  = tid >> 6;
    int lane = tid & 63;
    int row0 = bid * 64;
    int rowW = row0 + wid * 16;
    int rl   = lane & 15;
    int kc   = (lane >> 4) * 8;

    f32x4 acc[8];
#pragma unroll
    for (int n = 0; n < 8; ++n) acc[n] = (f32x4)0.f;

    int lr = wid * 16 + rl;
    const u32x4* B4 = reinterpret_cast<const u32x4*>(Wt);

    for (int c = 0; c < K / KC; ++c) {
        int k0 = c * KC;
        if (c > 0) __syncthreads();
        if constexpr (sizeof(TA) == 4) {
            // A: 64 x 64 fp32 = 1024 float4, 4 per thread
            const float4* A4 = reinterpret_cast<const float4*>(A);
            float4 av[4];
            u32x4  bv[4];
#pragma unroll
            for (int j = 0; j < 4; ++j) {
                int idx = tid + j * 256;
                int r = idx >> 4, c4 = idx & 15;
                int gr = row0 + r;
                if (gr >= M) gr = M - 1;
                av[j] = A4[(size_t)gr * (K / 4) + k0 / 4 + c4];
            }
#pragma unroll
            for (int j = 0; j < 4; ++j) {
                int idx = tid + j * 256;
                int r = idx >> 3, c8 = idx & 7;
                bv[j] = B4[(size_t)r * (K / 8) + k0 / 8 + c8];
            }
#pragma unroll
            for (int j = 0; j < 4; ++j) {
                int idx = tid + j * 256;
                int r = idx >> 4, c4 = idx & 15;
                f16 o[4] = {(f16)av[j].x, (f16)av[j].y, (f16)av[j].z, (f16)av[j].w};
                *reinterpret_cast<u64*>(&sa[r][c4 * 4]) = *reinterpret_cast<u64*>(o);
            }
#pragma unroll
            for (int j = 0; j < 4; ++j) {
                int idx = tid + j * 256;
                int r = idx >> 3, c8 = idx & 7;
                *reinterpret_cast<u32x4*>(&sb[r][c8 * 8]) = bv[j];
            }
        } else {
            // A: 64 x 64 f16 = 512 u32x4, 2 per thread
            const u32x4* A4 = reinterpret_cast<const u32x4*>(A);
            u32x4 av[2];
            u32x4 bv[4];
#pragma unroll
            for (int j = 0; j < 2; ++j) {
                int idx = tid + j * 256;
                int r = idx >> 3, c8 = idx & 7;
                int gr = row0 + r;
                if (gr >= M) gr = M - 1;
                av[j] = A4[(size_t)gr * (K / 8) + k0 / 8 + c8];
            }
#pragma unroll
            for (int j = 0; j < 4; ++j) {
                int idx = tid + j * 256;
                int r = idx >> 3, c8 = idx & 7;
                bv[j] = B4[(size_t)r * (K / 8) + k0 / 8 + c8];
            }
#pragma unroll
            for (int j = 0; j < 2; ++j) {
                int idx = tid + j * 256;
                int r = idx >> 3, c8 = idx & 7;
                *reinterpret_cast<u32x4*>(&sa[r][c8 * 8]) = av[j];
            }
#pragma unroll
            for (int j = 0; j < 4; ++j) {
                int idx = tid + j * 256;
                int r = idx >> 3, c8 = idx & 7;
                *reinterpret_cast<u32x4*>(&sb[r][c8 * 8]) = bv[j];
            }
        }
        __syncthreads();

#pragma unroll
        for (int kk = 0; kk < KC; kk += 32) {
            f16x8 aF = *reinterpret_cast<const f16x8*>(&sa[lr][kk + kc]);
#pragma unroll
            for (int n = 0; n < 8; ++n) {
                f16x8 bF = *reinterpret_cast<const f16x8*>(&sb[n * 16 + rl][kk + kc]);
                acc[n] = __builtin_amdgcn_mfma_f32_16x16x32_f16(aF, bF, acc[n], 0, 0, 0);
            }
        }
    }

#pragma unroll
    for (int n = 0; n < 8; ++n) {
        int col = n * 16 + rl;
        float bias = b[col];
#pragma unroll
        for (int j = 0; j < 4; ++j) {
            int row = rowW + 4 * (lane >> 4) + j;
            if (row < M) {
                float s = acc[n][j] + bias;
                if (RELU) s = fmaxf(s, 0.f);
                C[(size_t)row * 128 + col] = (f16)s;
            }
        }
    }
}

// ---- fused dispatch A: GEMM1 blocks || edge-scatter blocks (independent) ----

__global__ __launch_bounds__(256, 4)
void k_g1_scatter(const float* __restrict__ x, const f16* __restrict__ W1t,
                  const float* __restrict__ b1, f16* __restrict__ H0h,
                  const int* __restrict__ src, const int* __restrict__ dst,
                  const float* __restrict__ dinv, int* __restrict__ cursor,
                  int2* __restrict__ ew) {
    if ((int)blockIdx.x < GB_GEMM) {
        gemm_tile<IN_F, true, float>(x, W1t, b1, H0h, NNODES, blockIdx.x);
    } else {
        int t = (blockIdx.x - GB_GEMM) * 256 + threadIdx.x;
        if (t < NEDGES) {
            int s = src[t], d = dst[t];
            int pos = atomicAdd(&cursor[d], 1);
            ew[pos] = make_int2(s, __float_as_int(dinv[s] * dinv[d]));
        } else if (t < NEDGES + NNODES) {
            int i = t - NEDGES;
            int pos = atomicAdd(&cursor[i], 1);
            float di = dinv[i];
            ew[pos] = make_int2(i, __float_as_int(di * di));
        }
    }
}

// ---- fused dispatch B: GEMM2 blocks || per-node wave sort (independent) ----

__global__ __launch_bounds__(256, 4)
void k_g2_sort(const f16* __restrict__ H0h, const f16* __restrict__ W2t,
               const float* __restrict__ b2, f16* __restrict__ Hh0,
               const int* __restrict__ rp, int2* __restrict__ ew) {
    if ((int)blockIdx.x < GB_GEMM) {
        gemm_tile<HID_F, false, f16>(H0h, W2t, b2, Hh0, NNODES, blockIdx.x);
    } else {
        int node = (blockIdx.x - GB_GEMM) * 4 + (threadIdx.x >> 6);
        int lane = threadIdx.x & 63;
        if (node >= NNODES) return;
        int beg = rp[node], end = rp[node + 1];
        int deg = end - beg;
        if (deg > 64) return;  // leave unsorted (perf-only transform)
        int2 my = make_int2(0x7fffffff, 0);
        if (lane < deg) my = ew[beg + lane];
        int rank = 0;
        for (int k = 0; k < deg; ++k) {
            int sk = __shfl(my.x, k);
            rank += (sk < my.x) || (sk == my.x && k < lane);
        }
        if (lane < deg) ew[beg + rank] = my;
    }
}

// ---- propagation at width 128, H in fp16, accumulate fp32 ----
// 16 lanes per node, one u32x4 (8 halves) per lane.

template<bool RELU>
__global__ void k_proph(const u32* __restrict__ Hin, u32* __restrict__ Hout,
                        const int* __restrict__ rp, const int2* __restrict__ ew,
                        int n) {
    int grp  = threadIdx.x >> 4;   // 16 nodes per block
    int lane = threadIdx.x & 15;
    int node = blockIdx.x * 16 + grp;
    if (node >= n) return;
    int beg = rp[node], end = rp[node + 1];
    const u32x4* H4 = reinterpret_cast<const u32x4*>(Hin);  // row = 16 u32x4

    float acc[8];
#pragma unroll
    for (int i = 0; i < 8; ++i) acc[i] = 0.f;

    auto body = [&](int e) {
        int2 p   = ew[e];
        float ww = __int_as_float(p.y);
        u32x4 v  = H4[(size_t)p.x * 16 + lane];
#pragma unroll
        for (int q = 0; q < 4; ++q) {
            float2 f = upk(v[q]);
            acc[q * 2 + 0] += ww * f.x;
            acc[q * 2 + 1] += ww * f.y;
        }
    };

    int e = beg;
    for (; e + 1 < end; e += 2) { body(e); body(e + 1); }
    if (e < end) body(e);

    if (RELU) {
#pragma unroll
        for (int i = 0; i < 8; ++i) acc[i] = fmaxf(acc[i], 0.f);
    }
    u32x4 o;
#pragma unroll
    for (int q = 0; q < 4; ++q) o[q] = pk2(acc[q * 2], acc[q * 2 + 1]);
    reinterpret_cast<u32x4*>(Hout)[(size_t)node * 16 + lane] = o;
}

// ------------- classifier: G[M,16] = Ah[M,128](fp16) @ Wc + bc -------------

__global__ void k_cls_h(const u32* __restrict__ Ah, const float* __restrict__ Wc,
                        const float* __restrict__ bc, float* __restrict__ G, int M) {
    __shared__ float sa[64][132];
    __shared__ float4 sw4[512];
    int tid  = threadIdx.x;
    int row0 = blockIdx.x * 64;

    for (int idx = tid; idx < 512; idx += 256)
        sw4[idx] = reinterpret_cast<const float4*>(Wc)[idx];

    const uint4* A4 = reinterpret_cast<const uint4*>(Ah);
    for (int idx = tid; idx < 64 * 16; idx += 256) {
        int r = idx >> 4, c = idx & 15;
        int gr = row0 + r;
        uint4 v = (gr < M) ? A4[(size_t)gr * 16 + c]
                           : make_uint4(0u, 0u, 0u, 0u);
        float* dst = &sa[r][c * 8];
        const u32* vv = reinterpret_cast<const u32*>(&v);
#pragma unroll
        for (int q = 0; q < 4; ++q) {
            float2 f = upk(vv[q]);
            dst[q * 2 + 0] = f.x;
            dst[q * 2 + 1] = f.y;
        }
    }
    __syncthreads();

    int tc = tid & 3;
    int tr = tid >> 2;
    float4 acc = make_float4(0.f, 0.f, 0.f, 0.f);
    for (int k4 = 0; k4 < 32; ++k4) {
        float4 a = *reinterpret_cast<const float4*>(&sa[tr][k4 * 4]);
        const float* af = reinterpret_cast<const float*>(&a);
#pragma unroll
        for (int kk = 0; kk < 4; ++kk) {
            float4 wv = sw4[(k4 * 4 + kk) * 4 + tc];
            float av = af[kk];
            acc.x += av * wv.x; acc.y += av * wv.y;
            acc.z += av * wv.z; acc.w += av * wv.w;
        }
    }
    int r = row0 + tr;
    if (r < M) {
        float4 bb = reinterpret_cast<const float4*>(bc)[tc];
        acc.x += bb.x; acc.y += bb.y; acc.z += bb.z; acc.w += bb.w;
        reinterpret_cast<float4*>(G)[(size_t)r * 4 + tc] = acc;
    }
}

// ---- final hop at width 16, fp32 ----

__global__ void k_prop16(const float* __restrict__ Gin, float* __restrict__ Out,
                         const int* __restrict__ rp, const int2* __restrict__ ew,
                         int n) {
    int g    = blockIdx.x * 64 + (threadIdx.x >> 2);
    int lane = threadIdx.x & 3;
    if (g >= n) return;
    int beg = rp[g], end = rp[g + 1];
    const float4* G4 = reinterpret_cast<const float4*>(Gin);
    float ax = 0.f, ay = 0.f, az = 0.f, aw = 0.f;
    for (int e = beg; e < end; ++e) {
        int2 p   = ew[e];
        float ww = __int_as_float(p.y);
        float4 hv = G4[(size_t)p.x * 4 + lane];
        ax += ww * hv.x; ay += ww * hv.y; az += ww * hv.z; aw += ww * hv.w;
    }
    reinterpret_cast<float4*>(Out)[(size_t)g * 4 + lane] = make_float4(ax, ay, az, aw);
}

// ---------------- host launch ----------------

extern "C" void kernel_launch(void* const* d_in, const int* in_sizes, int n_in,
                              void* d_out, int out_size, void* d_ws, size_t ws_size,
                              hipStream_t stream) {
    const float* x  = (const float*)d_in[0];
    const float* W1 = (const float*)d_in[1];
    const float* b1 = (const float*)d_in[2];
    const float* W2 = (const float*)d_in[3];
    const float* b2 = (const float*)d_in[4];
    const float* Wc = (const float*)d_in[5];
    const float* bc = (const float*)d_in[6];
    const int*   ei = (const int*)d_in[7];
    const int* srcp = ei;
    const int* dstp = ei + NEDGES;
    float* out = (float*)d_out;

    char* p = (char*)d_ws;
    auto alloc = [&](size_t bytes) -> char* {
        char* r = p;
        p += (bytes + 255) & ~(size_t)255;
        return r;
    };
    int*   deg    = (int*)  alloc(NNODES * 4);
    float* dinv   = (float*)alloc(NNODES * 4);
    int*   rp     = (int*)  alloc((NNODES + 1) * 4);
    int*   cursor = (int*)  alloc(NNODES * 4);
    int*   bsums  = (int*)  alloc(256 * 4);
    int2*  ew     = (int2*) alloc((size_t)(NEDGES + NNODES) * 8);  // {src,w}
    f16*   W1t    = (f16*)  alloc((size_t)HID_F * IN_F * 2);   // W1^T fp16
    f16*   W2t    = (f16*)  alloc((size_t)HID_F * HID_F * 2);  // W2^T fp16
    f16*   H0h    = (f16*)  alloc((size_t)MPAD * HID_F * 2);   // gemm1 out (padded)
    u32*   Hh0    = (u32*)  alloc((size_t)MPAD * HID_F * 2);   // prop buffers
    u32*   Hh1    = (u32*)  alloc((size_t)NNODES * HID_F * 2);
    float* G      = (float*)alloc((size_t)NNODES * OUT_F * 4);

    const int T = 256;
    auto nb = [](int n, int t) { return (n + t - 1) / t; };

    // graph norm + CSR prefix (small kernels) + weight casts
    k_init_deg<<<nb(NNODES, T), T, 0, stream>>>(deg, NNODES);
    k_count<<<nb(NEDGES, T), T, 0, stream>>>(dstp, deg, NEDGES);
    k_dinv<<<nb(NNODES, T), T, 0, stream>>>(deg, dinv, NNODES);
    int NB = nb(NNODES, 256);
    k_scan1<<<NB, 256, 0, stream>>>(deg, bsums, NNODES);
    k_scan2<<<1, 1, 0, stream>>>(bsums, NB, rp, NNODES);
    k_scan3<<<NB, 256, 0, stream>>>(deg, bsums, rp, cursor, NNODES);
    k_cast_wt<IN_F,  HID_F><<<nb(IN_F * HID_F, T), T, 0, stream>>>(W1, W1t);
    k_cast_wt<HID_F, HID_F><<<nb(HID_F * HID_F, T), T, 0, stream>>>(W2, W2t);

    // fused A: GEMM1 (f32-in -> f16 relu) || edge scatter
    int SCB = nb(NEDGES + NNODES, 256);
    k_g1_scatter<<<GB_GEMM + SCB, 256, 0, stream>>>(x, W1t, b1, H0h,
                                                    srcp, dstp, dinv, cursor, ew);
    // fused B: GEMM2 (f16 -> f16) || per-node wave sort
    int SWB = nb(NNODES, 4);
    k_g2_sort<<<GB_GEMM + SWB, 256, 0, stream>>>(H0h, W2t, b2, (f16*)Hh0, rp, ew);

    // 30 hops at width 128 in fp16, relu fused into last hop
    u32* cur = Hh0;
    u32* nxt = Hh1;
    int PB = nb(NNODES, 16);
    for (int i = 0; i < HOPS; ++i) {
        if (i == HOPS - 1)
            k_proph<true ><<<PB, 256, 0, stream>>>(cur, nxt, rp, ew, NNODES);
        else
            k_proph<false><<<PB, 256, 0, stream>>>(cur, nxt, rp, ew, NNODES);
        u32* t = cur; cur = nxt; nxt = t;
    }

    // classifier + final hop at width 16
    k_cls_h<<<nb(NNODES, 64), 256, 0, stream>>>(cur, Wc, bc, G, NNODES);
    k_prop16<<<nb(NNODES, 64), 256, 0, stream>>>(G, out, rp, ew, NNODES);
}

// Round 15
// 1035.186 us; speedup vs baseline: 1.3532x; 1.0177x over previous
//
#include <hip/hip_runtime.h>
#include <hip/hip_fp16.h>

#define NNODES 50000
#define NEDGES 800000
#define IN_F   256
#define HID_F  128
#define OUT_F  16
#define HOPS   30
#define MPAD   50048   // NNODES rounded up to 64-row GEMM tiles
#define GB_GEMM (MPAD / 64)

typedef unsigned int u32;
typedef unsigned long long u64;
typedef _Float16 f16;
typedef f16 f16x8 __attribute__((ext_vector_type(8)));
typedef float f32x4 __attribute__((ext_vector_type(4)));
typedef u32 u32x4 __attribute__((ext_vector_type(4)));

union U32H2 { u32 u; __half2 h; };

__device__ inline float2 upk(u32 v) {
    U32H2 t; t.u = v;
    return __half22float2(t.h);
}
__device__ inline u32 pk2(float a, float b) {
    U32H2 t; t.h = __floats2half2_rn(a, b);
    return t.u;
}

// ---------------- graph setup kernels ----------------

__global__ void k_init_deg(int* __restrict__ deg, int n) {
    int i = blockIdx.x * blockDim.x + threadIdx.x;
    if (i < n) deg[i] = 1;  // self-loop
}

__global__ void k_count(const int* __restrict__ dst, int* __restrict__ deg, int e) {
    int i = blockIdx.x * blockDim.x + threadIdx.x;
    if (i < e) atomicAdd(&deg[dst[i]], 1);
}

__global__ void k_dinv(const int* __restrict__ deg, float* __restrict__ dinv, int n) {
    int i = blockIdx.x * blockDim.x + threadIdx.x;
    if (i < n) dinv[i] = rsqrtf((float)deg[i]);
}

__global__ void k_scan1(const int* __restrict__ deg, int* __restrict__ bsums, int n) {
    __shared__ int sh[256];
    int tid = threadIdx.x;
    int i = blockIdx.x * 256 + tid;
    sh[tid] = (i < n) ? deg[i] : 0;
    __syncthreads();
    for (int ofs = 128; ofs > 0; ofs >>= 1) {
        if (tid < ofs) sh[tid] += sh[tid + ofs];
        __syncthreads();
    }
    if (tid == 0) bsums[blockIdx.x] = sh[0];
}

__global__ void k_scan2(int* __restrict__ bsums, int nb, int* __restrict__ rp, int n) {
    if (threadIdx.x == 0 && blockIdx.x == 0) {
        int run = 0;
        for (int b = 0; b < nb; ++b) { int t = bsums[b]; bsums[b] = run; run += t; }
        rp[n] = run;
    }
}

__global__ void k_scan3(const int* __restrict__ deg, const int* __restrict__ bsums,
                        int* __restrict__ rp, int* __restrict__ cursor, int n) {
    __shared__ int sh[256];
    int tid = threadIdx.x;
    int i = blockIdx.x * 256 + tid;
    int v = (i < n) ? deg[i] : 0;
    sh[tid] = v;
    __syncthreads();
    for (int ofs = 1; ofs < 256; ofs <<= 1) {
        int t = 0;
        if (tid >= ofs) t = sh[tid - ofs];
        __syncthreads();
        sh[tid] += t;
        __syncthreads();
    }
    if (i < n) {
        int excl = sh[tid] - v + bsums[blockIdx.x];
        rp[i] = excl;
        cursor[i] = excl;
    }
}

// W[K][NC] fp32 -> Wt[NC][K] fp16
template<int K, int NC>
__global__ void k_cast_wt(const float* __restrict__ W, f16* __restrict__ Wt) {
    int i = blockIdx.x * blockDim.x + threadIdx.x;
    if (i < K * NC) {
        int k = i / NC, c = i % NC;
        Wt[(size_t)c * K + k] = (f16)W[i];
    }
}

// ---- GEMM tile device body: C[M,128](fp16) = (relu?)(A[M,K] @ Wt^T + b) ----
// 64-row tile, 4 waves x 16 rows, N_rep=8, KC=64 chunks, both operands
// staged through LDS with register-batched loads.

template<int K, bool RELU, typename TA>
__device__ void gemm_tile(const TA* __restrict__ A, const f16* __restrict__ Wt,
                          const float* __restrict__ b, f16* __restrict__ C,
                          int M, int bid) {
    constexpr int KC = 64;
    __shared__ f16 sa[64][KC + 8];
    __shared__ f16 sb[128][KC + 8];
    int tid  = threadIdx.x;
    int wid  = tid >> 6;
    int lane = tid & 63;
    int row0 = bid * 64;
    int rowW = row0 + wid * 16;
    int rl   = lane & 15;
    int kc   = (lane >> 4) * 8;

    f32x4 acc[8];
#pragma unroll
    for (int n = 0; n < 8; ++n) acc[n] = (f32x4)0.f;

    int lr = wid * 16 + rl;
    const u32x4* B4 = reinterpret_cast<const u32x4*>(Wt);

    for (int c = 0; c < K / KC; ++c) {
        int k0 = c * KC;
        if (c > 0) __syncthreads();
        if constexpr (sizeof(TA) == 4) {
            const float4* A4 = reinterpret_cast<const float4*>(A);
            float4 av[4];
            u32x4  bv[4];
#pragma unroll
            for (int j = 0; j < 4; ++j) {
                int idx = tid + j * 256;
                int r = idx >> 4, c4 = idx & 15;
                int gr = row0 + r;
                if (gr >= M) gr = M - 1;
                av[j] = A4[(size_t)gr * (K / 4) + k0 / 4 + c4];
            }
#pragma unroll
            for (int j = 0; j < 4; ++j) {
                int idx = tid + j * 256;
                int r = idx >> 3, c8 = idx & 7;
                bv[j] = B4[(size_t)r * (K / 8) + k0 / 8 + c8];
            }
#pragma unroll
            for (int j = 0; j < 4; ++j) {
                int idx = tid + j * 256;
                int r = idx >> 4, c4 = idx & 15;
                f16 o[4] = {(f16)av[j].x, (f16)av[j].y, (f16)av[j].z, (f16)av[j].w};
                *reinterpret_cast<u64*>(&sa[r][c4 * 4]) = *reinterpret_cast<u64*>(o);
            }
#pragma unroll
            for (int j = 0; j < 4; ++j) {
                int idx = tid + j * 256;
                int r = idx >> 3, c8 = idx & 7;
                *reinterpret_cast<u32x4*>(&sb[r][c8 * 8]) = bv[j];
            }
        } else {
            const u32x4* A4 = reinterpret_cast<const u32x4*>(A);
            u32x4 av[2];
            u32x4 bv[4];
#pragma unroll
            for (int j = 0; j < 2; ++j) {
                int idx = tid + j * 256;
                int r = idx >> 3, c8 = idx & 7;
                int gr = row0 + r;
                if (gr >= M) gr = M - 1;
                av[j] = A4[(size_t)gr * (K / 8) + k0 / 8 + c8];
            }
#pragma unroll
            for (int j = 0; j < 4; ++j) {
                int idx = tid + j * 256;
                int r = idx >> 3, c8 = idx & 7;
                bv[j] = B4[(size_t)r * (K / 8) + k0 / 8 + c8];
            }
#pragma unroll
            for (int j = 0; j < 2; ++j) {
                int idx = tid + j * 256;
                int r = idx >> 3, c8 = idx & 7;
                *reinterpret_cast<u32x4*>(&sa[r][c8 * 8]) = av[j];
            }
#pragma unroll
            for (int j = 0; j < 4; ++j) {
                int idx = tid + j * 256;
                int r = idx >> 3, c8 = idx & 7;
                *reinterpret_cast<u32x4*>(&sb[r][c8 * 8]) = bv[j];
            }
        }
        __syncthreads();

#pragma unroll
        for (int kk = 0; kk < KC; kk += 32) {
            f16x8 aF = *reinterpret_cast<const f16x8*>(&sa[lr][kk + kc]);
#pragma unroll
            for (int n = 0; n < 8; ++n) {
                f16x8 bF = *reinterpret_cast<const f16x8*>(&sb[n * 16 + rl][kk + kc]);
                acc[n] = __builtin_amdgcn_mfma_f32_16x16x32_f16(aF, bF, acc[n], 0, 0, 0);
            }
        }
    }

#pragma unroll
    for (int n = 0; n < 8; ++n) {
        int col = n * 16 + rl;
        float bias = b[col];
#pragma unroll
        for (int j = 0; j < 4; ++j) {
            int row = rowW + 4 * (lane >> 4) + j;
            if (row < M) {
                float s = acc[n][j] + bias;
                if (RELU) s = fmaxf(s, 0.f);
                C[(size_t)row * 128 + col] = (f16)s;
            }
        }
    }
}

// ---- fused dispatch A: GEMM1 blocks || edge-scatter blocks (independent) ----

__global__ __launch_bounds__(256, 4)
void k_g1_scatter(const float* __restrict__ x, const f16* __restrict__ W1t,
                  const float* __restrict__ b1, f16* __restrict__ H0h,
                  const int* __restrict__ src, const int* __restrict__ dst,
                  const float* __restrict__ dinv, int* __restrict__ cursor,
                  int2* __restrict__ ew) {
    if ((int)blockIdx.x < GB_GEMM) {
        gemm_tile<IN_F, true, float>(x, W1t, b1, H0h, NNODES, blockIdx.x);
    } else {
        int t = (blockIdx.x - GB_GEMM) * 256 + threadIdx.x;
        if (t < NEDGES) {
            int s = src[t], d = dst[t];
            int pos = atomicAdd(&cursor[d], 1);
            ew[pos] = make_int2(s, __float_as_int(dinv[s] * dinv[d]));
        } else if (t < NEDGES + NNODES) {
            int i = t - NEDGES;
            int pos = atomicAdd(&cursor[i], 1);
            float di = dinv[i];
            ew[pos] = make_int2(i, __float_as_int(di * di));
        }
    }
}

// ---- fused dispatch B: GEMM2 blocks || per-node wave sort (independent) ----

__global__ __launch_bounds__(256, 4)
void k_g2_sort(const f16* __restrict__ H0h, const f16* __restrict__ W2t,
               const float* __restrict__ b2, f16* __restrict__ Hh0,
               const int* __restrict__ rp, int2* __restrict__ ew) {
    if ((int)blockIdx.x < GB_GEMM) {
        gemm_tile<HID_F, false, f16>(H0h, W2t, b2, Hh0, NNODES, blockIdx.x);
    } else {
        int node = (blockIdx.x - GB_GEMM) * 4 + (threadIdx.x >> 6);
        int lane = threadIdx.x & 63;
        if (node >= NNODES) return;
        int beg = rp[node], end = rp[node + 1];
        int deg = end - beg;
        if (deg > 64) return;  // leave unsorted (perf-only transform)
        int2 my = make_int2(0x7fffffff, 0);
        if (lane < deg) my = ew[beg + lane];
        int rank = 0;
        for (int k = 0; k < deg; ++k) {
            int sk = __shfl(my.x, k);
            rank += (sk < my.x) || (sk == my.x && k < lane);
        }
        if (lane < deg) ew[beg + rank] = my;
    }
}

// ---- propagation at width 128, H in fp16, accumulate fp32 ----
// 16 lanes per node, one u32x4 (8 halves) per lane; edge loop unrolled x4
// to keep 4 independent gathers in flight per lane group.

template<bool RELU>
__global__ void k_proph(const u32* __restrict__ Hin, u32* __restrict__ Hout,
                        const int* __restrict__ rp, const int2* __restrict__ ew,
                        int n) {
    int grp  = threadIdx.x >> 4;   // 16 nodes per block
    int lane = threadIdx.x & 15;
    int node = blockIdx.x * 16 + grp;
    if (node >= n) return;
    int beg = rp[node], end = rp[node + 1];
    const u32x4* H4 = reinterpret_cast<const u32x4*>(Hin);  // row = 16 u32x4

    float acc[8];
#pragma unroll
    for (int i = 0; i < 8; ++i) acc[i] = 0.f;

    auto body = [&](int e) {
        int2 p   = ew[e];
        float ww = __int_as_float(p.y);
        u32x4 v  = H4[(size_t)p.x * 16 + lane];
#pragma unroll
        for (int q = 0; q < 4; ++q) {
            float2 f = upk(v[q]);
            acc[q * 2 + 0] += ww * f.x;
            acc[q * 2 + 1] += ww * f.y;
        }
    };

    int e = beg;
    for (; e + 3 < end; e += 4) { body(e); body(e + 1); body(e + 2); body(e + 3); }
    for (; e < end; ++e) body(e);

    if (RELU) {
#pragma unroll
        for (int i = 0; i < 8; ++i) acc[i] = fmaxf(acc[i], 0.f);
    }
    u32x4 o;
#pragma unroll
    for (int q = 0; q < 4; ++q) o[q] = pk2(acc[q * 2], acc[q * 2 + 1]);
    reinterpret_cast<u32x4*>(Hout)[(size_t)node * 16 + lane] = o;
}

// ------------- classifier: G[M,16] = Ah[M,128](fp16) @ Wc + bc -------------

__global__ void k_cls_h(const u32* __restrict__ Ah, const float* __restrict__ Wc,
                        const float* __restrict__ bc, float* __restrict__ G, int M) {
    __shared__ float sa[64][132];
    __shared__ float4 sw4[512];
    int tid  = threadIdx.x;
    int row0 = blockIdx.x * 64;

    for (int idx = tid; idx < 512; idx += 256)
        sw4[idx] = reinterpret_cast<const float4*>(Wc)[idx];

    const uint4* A4 = reinterpret_cast<const uint4*>(Ah);
    for (int idx = tid; idx < 64 * 16; idx += 256) {
        int r = idx >> 4, c = idx & 15;
        int gr = row0 + r;
        uint4 v = (gr < M) ? A4[(size_t)gr * 16 + c]
                           : make_uint4(0u, 0u, 0u, 0u);
        float* dst = &sa[r][c * 8];
        const u32* vv = reinterpret_cast<const u32*>(&v);
#pragma unroll
        for (int q = 0; q < 4; ++q) {
            float2 f = upk(vv[q]);
            dst[q * 2 + 0] = f.x;
            dst[q * 2 + 1] = f.y;
        }
    }
    __syncthreads();

    int tc = tid & 3;
    int tr = tid >> 2;
    float4 acc = make_float4(0.f, 0.f, 0.f, 0.f);
    for (int k4 = 0; k4 < 32; ++k4) {
        float4 a = *reinterpret_cast<const float4*>(&sa[tr][k4 * 4]);
        const float* af = reinterpret_cast<const float*>(&a);
#pragma unroll
        for (int kk = 0; kk < 4; ++kk) {
            float4 wv = sw4[(k4 * 4 + kk) * 4 + tc];
            float av = af[kk];
            acc.x += av * wv.x; acc.y += av * wv.y;
            acc.z += av * wv.z; acc.w += av * wv.w;
        }
    }
    int r = row0 + tr;
    if (r < M) {
        float4 bb = reinterpret_cast<const float4*>(bc)[tc];
        acc.x += bb.x; acc.y += bb.y; acc.z += bb.z; acc.w += bb.w;
        reinterpret_cast<float4*>(G)[(size_t)r * 4 + tc] = acc;
    }
}

// ---- final hop at width 16, fp32 ----

__global__ void k_prop16(const float* __restrict__ Gin, float* __restrict__ Out,
                         const int* __restrict__ rp, const int2* __restrict__ ew,
                         int n) {
    int g    = blockIdx.x * 64 + (threadIdx.x >> 2);
    int lane = threadIdx.x & 3;
    if (g >= n) return;
    int beg = rp[g], end = rp[g + 1];
    const float4* G4 = reinterpret_cast<const float4*>(Gin);
    float ax = 0.f, ay = 0.f, az = 0.f, aw = 0.f;
    for (int e = beg; e < end; ++e) {
        int2 p   = ew[e];
        float ww = __int_as_float(p.y);
        float4 hv = G4[(size_t)p.x * 4 + lane];
        ax += ww * hv.x; ay += ww * hv.y; az += ww * hv.z; aw += ww * hv.w;
    }
    reinterpret_cast<float4*>(Out)[(size_t)g * 4 + lane] = make_float4(ax, ay, az, aw);
}

// ---------------- host launch ----------------

extern "C" void kernel_launch(void* const* d_in, const int* in_sizes, int n_in,
                              void* d_out, int out_size, void* d_ws, size_t ws_size,
                              hipStream_t stream) {
    const float* x  = (const float*)d_in[0];
    const float* W1 = (const float*)d_in[1];
    const float* b1 = (const float*)d_in[2];
    const float* W2 = (const float*)d_in[3];
    const float* b2 = (const float*)d_in[4];
    const float* Wc = (const float*)d_in[5];
    const float* bc = (const float*)d_in[6];
    const int*   ei = (const int*)d_in[7];
    const int* srcp = ei;
    const int* dstp = ei + NEDGES;
    float* out = (float*)d_out;

    char* p = (char*)d_ws;
    auto alloc = [&](size_t bytes) -> char* {
        char* r = p;
        p += (bytes + 255) & ~(size_t)255;
        return r;
    };
    int*   deg    = (int*)  alloc(NNODES * 4);
    float* dinv   = (float*)alloc(NNODES * 4);
    int*   rp     = (int*)  alloc((NNODES + 1) * 4);
    int*   cursor = (int*)  alloc(NNODES * 4);
    int*   bsums  = (int*)  alloc(256 * 4);
    int2*  ew     = (int2*) alloc((size_t)(NEDGES + NNODES) * 8);  // {src,w}
    f16*   W1t    = (f16*)  alloc((size_t)HID_F * IN_F * 2);   // W1^T fp16
    f16*   W2t    = (f16*)  alloc((size_t)HID_F * HID_F * 2);  // W2^T fp16
    f16*   H0h    = (f16*)  alloc((size_t)MPAD * HID_F * 2);   // gemm1 out (padded)
    u32*   Hh0    = (u32*)  alloc((size_t)MPAD * HID_F * 2);   // prop buffers
    u32*   Hh1    = (u32*)  alloc((size_t)NNODES * HID_F * 2);
    float* G      = (float*)alloc((size_t)NNODES * OUT_F * 4);

    const int T = 256;
    auto nb = [](int n, int t) { return (n + t - 1) / t; };

    // graph norm + CSR prefix (small kernels) + weight casts
    k_init_deg<<<nb(NNODES, T), T, 0, stream>>>(deg, NNODES);
    k_count<<<nb(NEDGES, T), T, 0, stream>>>(dstp, deg, NEDGES);
    k_dinv<<<nb(NNODES, T), T, 0, stream>>>(deg, dinv, NNODES);
    int NB = nb(NNODES, 256);
    k_scan1<<<NB, 256, 0, stream>>>(deg, bsums, NNODES);
    k_scan2<<<1, 1, 0, stream>>>(bsums, NB, rp, NNODES);
    k_scan3<<<NB, 256, 0, stream>>>(deg, bsums, rp, cursor, NNODES);
    k_cast_wt<IN_F,  HID_F><<<nb(IN_F * HID_F, T), T, 0, stream>>>(W1, W1t);
    k_cast_wt<HID_F, HID_F><<<nb(HID_F * HID_F, T), T, 0, stream>>>(W2, W2t);

    // fused A: GEMM1 (f32-in -> f16 relu) || edge scatter
    int SCB = nb(NEDGES + NNODES, 256);
    k_g1_scatter<<<GB_GEMM + SCB, 256, 0, stream>>>(x, W1t, b1, H0h,
                                                    srcp, dstp, dinv, cursor, ew);
    // fused B: GEMM2 (f16 -> f16) || per-node wave sort
    int SWB = nb(NNODES, 4);
    k_g2_sort<<<GB_GEMM + SWB, 256, 0, stream>>>(H0h, W2t, b2, (f16*)Hh0, rp, ew);

    // 30 hops at width 128 in fp16, relu fused into last hop
    u32* cur = Hh0;
    u32* nxt = Hh1;
    int PB = nb(NNODES, 16);
    for (int i = 0; i < HOPS; ++i) {
        if (i == HOPS - 1)
            k_proph<true ><<<PB, 256, 0, stream>>>(cur, nxt, rp, ew, NNODES);
        else
            k_proph<false><<<PB, 256, 0, stream>>>(cur, nxt, rp, ew, NNODES);
        u32* t = cur; cur = nxt; nxt = t;
    }

    // classifier + final hop at width 16
    k_cls_h<<<nb(NNODES, 64), 256, 0, stream>>>(cur, Wc, bc, G, NNODES);
    k_prop16<<<nb(NNODES, 64), 256, 0, stream>>>(G, out, rp, ew, NNODES);
}